// Round 7
// baseline (148.696 us; speedup 1.0000x reference)
//
#include <hip/hip_runtime.h>
#include <hip/hip_fp16.h>

// Trilinear 3D-LUT interpolation (image-adaptive-3DLUT forward).
// lut: [3, 33, 33, 33] fp32, x: [4, 3, 1024, 1024] fp32 in [0,1], out same as x.
//
// R10: R9 + ONE change: deferred-store switches. R6/R9's channel switch used
// __syncthreads, whose implicit s_waitcnt vmcnt(0) drained the finished
// channel's OUTPUT STORES along with the LUT DMA -- stores never touch LDS,
// so that wait is pure exposed latency (~1-2us/switch). New protocol:
//   channel c outputs -> VGPRs (4x float4, not stored in-phase)
//   switch: s_barrier                (all waves consumed their LDS reads)
//           stage(c+1)               (9 global_load_lds, oldest in queue)
//           store channel-c outputs  (overlaps the DMA)
//           s_waitcnt vmcnt(4)       (in-order retire => all 9 DMA done;
//                                     the 4 newest stores may stay in flight)
//           s_barrier                (new LUT visible to all waves)
// Stores are never waited on anywhere (only the implicit end-of-kernel
// drain). sched_barrier(0) pins ordering at every step (rule #18/#21).
// Everything else is R9: counted-vmcnt prologue, fp16 r-pair LUT in ws,
// 256 blocks x 1024 threads, 1 block/CU, x read exactly once.

#define LUT_D     33
#define LUT_DD    (LUT_D * LUT_D)            // 1089
#define LUT_N     (LUT_D * LUT_D * LUT_D)    // 35937
#define CH_STRIDE 35940                      // u32 per channel in ws, 16B-aligned
#define STAGE_G   (CH_STRIDE / 4)            // 8985 dwordx4 groups per channel
#define HW4       (1024 * 1024 / 4)          // 262144 = 2^18 float4/plane
#define NGROUPS   (4 * HW4)                  // 2^20 float4 groups per plane-set
#define NCHUNKS   256
#define THREADS   1024
#define ITERS     (NGROUPS / NCHUNKS / THREADS)  // 4

typedef float vfloat4 __attribute__((ext_vector_type(4)));

__device__ __forceinline__ unsigned int pack2(float a, float b) {
    union { __half2 h; unsigned int u; } cv;
    cv.h = __floats2half2_rn(a, b);
    return cv.u;
}
__device__ __forceinline__ float2 unpack2(unsigned int p) {
    union { unsigned int u; __half2 h; } cv;
    cv.u = p;
    return __half22float2(cv.h);
}

// ---- Pass 1: pack lut fp32 -> fp16 r-pairs: ws[c*CH_STRIDE+i] = (v[i], v[i+1])
__global__ __launch_bounds__(256)
void lut_pack_kernel(const float* __restrict__ lut, unsigned int* __restrict__ W) {
    const int t = blockIdx.x * 256 + (int)threadIdx.x;
    if (t >= 3 * LUT_N) return;
    const int c = t / LUT_N;
    const int i = t - c * LUT_N;
    const float a = lut[t];
    const float b = (i + 1 < LUT_N) ? lut[t + 1] : 0.0f;
    W[c * CH_STRIDE + i] = pack2(a, b);
}

// ---- Pass 2: main interpolation, one block per chunk (1 block/CU).
__global__ __launch_bounds__(THREADS)
void lut3d_trilerp_kernel(const unsigned int* __restrict__ Wsrc,
                          const float* __restrict__ x,
                          float* __restrict__ out) {
    extern __shared__ __align__(16) unsigned int W[];  // CH_STRIDE u32 = 143,760 B

    const int t  = (int)threadIdx.x;
    const int g0 = (int)blockIdx.x * (NGROUPS / NCHUNKS) + t;

    const float4* x4 = (const float4*)x;
    float4*       o4 = (float4*)out;

    auto stage = [&](int c) {
#pragma unroll
        for (int s = 0; s < 9; ++s) {
            const int gid = s * THREADS + t;
            if (gid < STAGE_G) {
                __builtin_amdgcn_global_load_lds(
                    (const __attribute__((address_space(1))) void*)(Wsrc + c * CH_STRIDE + gid * 4),
                    (__attribute__((address_space(3))) void*)(W + gid * 4),
                    16, 0, 0);
            }
        }
    };

    // gather + lerp one pixel-quad into a register float4 (no store)
    auto quadv = [&](const int idx4[4], const float dr4[4], const float dg4[4],
                     const float db4[4]) -> vfloat4 {
        unsigned int q00[4], q01[4], q10[4], q11[4];
#pragma unroll
        for (int k = 0; k < 4; ++k) {
            q00[k] = W[idx4[k]];                  // (c000, c001) r-pair
            q01[k] = W[idx4[k] + LUT_D];          // (c010, c011)
            q10[k] = W[idx4[k] + LUT_DD];         // (c100, c101)
            q11[k] = W[idx4[k] + LUT_DD + LUT_D]; // (c110, c111)
        }
        float oo[4];
#pragma unroll
        for (int k = 0; k < 4; ++k) {
            const float2 a00 = unpack2(q00[k]);
            const float2 a01 = unpack2(q01[k]);
            const float2 a10 = unpack2(q10[k]);
            const float2 a11 = unpack2(q11[k]);
            const float l00 = a00.x + dr4[k] * (a00.y - a00.x);  // r-lerp
            const float l01 = a01.x + dr4[k] * (a01.y - a01.x);
            const float l10 = a10.x + dr4[k] * (a10.y - a10.x);
            const float l11 = a11.x + dr4[k] * (a11.y - a11.x);
            const float l0  = l00 + dg4[k] * (l01 - l00);        // g-lerp
            const float l1  = l10 + dg4[k] * (l11 - l10);
            oo[k] = l0 + db4[k] * (l1 - l0);                     // b-lerp
        }
        vfloat4 v = {oo[0], oo[1], oo[2], oo[3]};
        return v;
    };

    // ---- Prologue: DMA first, x loads second, counted-vmcnt barrier (R9).
    stage(0);                              // 9 oldest VMEM ops = LUT DMA
    __builtin_amdgcn_sched_barrier(0);     // x loads must not move above DMA

    int    ibs[ITERS];
    float4 R[ITERS], G[ITERS], B[ITERS];
#pragma unroll
    for (int it = 0; it < ITERS; ++it) {
        const int g  = g0 + it * THREADS;
        const int bi = g >> 18, hw4 = g & (HW4 - 1);
        ibs[it] = bi * 3 * HW4 + hw4;
        R[it] = x4[ibs[it]];
        G[it] = x4[ibs[it] + HW4];
        B[it] = x4[ibs[it] + 2 * HW4];
    }
    __builtin_amdgcn_sched_barrier(0);     // x loads must not sink below wait
    asm volatile("s_waitcnt vmcnt(12)" ::: "memory");  // 9 DMA done; 12 x in flight
    __builtin_amdgcn_s_barrier();          // W[ch0] visible to all waves
    __builtin_amdgcn_sched_barrier(0);     // no LDS read hoists above barrier

    // ---- Channel 0: idx+deltas per iter (staggered x waits), results -> regs.
    int   idx[ITERS][4];
    float dr[ITERS][4], dg[ITERS][4], db[ITERS][4];
    vfloat4 O0[ITERS];
#pragma unroll
    for (int it = 0; it < ITERS; ++it) {
        const float rr[4] = {R[it].x, R[it].y, R[it].z, R[it].w};
        const float gw[4] = {G[it].x, G[it].y, G[it].z, G[it].w};
        const float bw[4] = {B[it].x, B[it].y, B[it].z, B[it].w};
#pragma unroll
        for (int k = 0; k < 4; ++k) {
            const float sr = rr[k] * 32.0f;
            const float sg = gw[k] * 32.0f;
            const float sb = bw[k] * 32.0f;
            const float fr = fminf(fmaxf(floorf(sr), 0.0f), 31.0f);
            const float fg = fminf(fmaxf(floorf(sg), 0.0f), 31.0f);
            const float fb = fminf(fmaxf(floorf(sb), 0.0f), 31.0f);
            dr[it][k] = sr - fr;
            dg[it][k] = sg - fg;
            db[it][k] = sb - fb;
            idx[it][k] = ((int)fb * LUT_D + (int)fg) * LUT_D + (int)fr;
        }
        O0[it] = quadv(idx[it], dr[it], dg[it], db[it]);
    }

    // ---- Switch 0->1: barrier, DMA, store ch0 (overlaps DMA), counted wait.
    __builtin_amdgcn_sched_barrier(0);
    __builtin_amdgcn_s_barrier();          // all waves consumed ch0 LDS reads
    __builtin_amdgcn_sched_barrier(0);
    stage(1);
    __builtin_amdgcn_sched_barrier(0);
#pragma unroll
    for (int it = 0; it < ITERS; ++it)
        __builtin_nontemporal_store(O0[it], (vfloat4*)&o4[ibs[it]]);
    __builtin_amdgcn_sched_barrier(0);
    asm volatile("s_waitcnt vmcnt(4)" ::: "memory");   // 9 DMA retired; stores fly
    __builtin_amdgcn_s_barrier();          // W[ch1] visible
    __builtin_amdgcn_sched_barrier(0);

    // ---- Channel 1 -> regs.
    vfloat4 O1[ITERS];
#pragma unroll
    for (int it = 0; it < ITERS; ++it)
        O1[it] = quadv(idx[it], dr[it], dg[it], db[it]);

    // ---- Switch 1->2.
    __builtin_amdgcn_sched_barrier(0);
    __builtin_amdgcn_s_barrier();
    __builtin_amdgcn_sched_barrier(0);
    stage(2);
    __builtin_amdgcn_sched_barrier(0);
#pragma unroll
    for (int it = 0; it < ITERS; ++it)
        __builtin_nontemporal_store(O1[it], (vfloat4*)&o4[ibs[it] + HW4]);
    __builtin_amdgcn_sched_barrier(0);
    asm volatile("s_waitcnt vmcnt(4)" ::: "memory");   // old stores + 9 DMA retired
    __builtin_amdgcn_s_barrier();          // W[ch2] visible
    __builtin_amdgcn_sched_barrier(0);

    // ---- Channel 2: compute + store immediately (no further LDS overwrite).
#pragma unroll
    for (int it = 0; it < ITERS; ++it) {
        const vfloat4 v = quadv(idx[it], dr[it], dg[it], db[it]);
        __builtin_nontemporal_store(v, (vfloat4*)&o4[ibs[it] + 2 * HW4]);
    }
}

extern "C" void kernel_launch(void* const* d_in, const int* in_sizes, int n_in,
                              void* d_out, int out_size, void* d_ws, size_t ws_size,
                              hipStream_t stream) {
    const float*  lut = (const float*)d_in[0];   // [3, 33, 33, 33]
    const float*  x   = (const float*)d_in[1];   // [4, 3, 1024, 1024]
    float*        out = (float*)d_out;
    unsigned int* W   = (unsigned int*)d_ws;     // 3*CH_STRIDE u32 = 431,280 B

    const int pack_grid = (3 * LUT_N + 255) / 256;   // 422
    lut_pack_kernel<<<pack_grid, 256, 0, stream>>>(lut, W);

    const size_t lds_bytes = (size_t)CH_STRIDE * 4;  // 143,760 B -> 1 block/CU
    lut3d_trilerp_kernel<<<NCHUNKS, THREADS, lds_bytes, stream>>>(W, x, out);
}

// Round 8
// 111.441 us; speedup vs baseline: 1.3343x; 1.3343x over previous
//
#include <hip/hip_runtime.h>
#include <hip/hip_fp16.h>

// Trilinear 3D-LUT interpolation (image-adaptive-3DLUT forward).
// lut: [3, 33, 33, 33] fp32, x: [4, 3, 1024, 1024] fp32 in [0,1], out same as x.
//
// R11 = exact revert to R6, the measured-best kernel (112.2 us total).
// Session ledger (total dur_us; fixed harness overhead ~78 us of poison
// fills + restores is included in all numbers):
//   R6  112.2  <- this kernel: x read once, per-channel LDS re-stage via
//                 global_load_lds DMA, fp16 r-pair LUT from a ws pack pass
//   R7  118.7  channel-major blocks (3x device x reads cost more at L3)
//   R8  117.0  packed fp16 state + per-iter load streaming (shallow pipe)
//   R9  114.1  counted-vmcnt prologue (ch0 is BW-bound; overlap gain ~ noise)
//   R10 148.7  deferred-store switches -> VGPR spill (WRITE 49->148 MB)
// Remaining theoretical gap (~8 us: ch0 x-drain overlap, 2x ~1.5us switch
// DMA) has been attacked four ways; all regressed or were noise. The switch
// floor is barrier skew + 143.7 KB/CU from L2 (~1 us) -- structural.

#define LUT_D     33
#define LUT_DD    (LUT_D * LUT_D)            // 1089
#define LUT_N     (LUT_D * LUT_D * LUT_D)    // 35937
#define CH_STRIDE 35940                      // u32 per channel in ws, 16B-aligned
#define STAGE_G   (CH_STRIDE / 4)            // 8985 dwordx4 groups per channel
#define HW4       (1024 * 1024 / 4)          // 262144 = 2^18 float4/plane
#define NGROUPS   (4 * HW4)                  // 2^20 float4 groups per plane-set
#define NCHUNKS   256
#define THREADS   1024
#define ITERS     (NGROUPS / NCHUNKS / THREADS)  // 4

typedef float vfloat4 __attribute__((ext_vector_type(4)));

__device__ __forceinline__ unsigned int pack2(float a, float b) {
    union { __half2 h; unsigned int u; } cv;
    cv.h = __floats2half2_rn(a, b);
    return cv.u;
}
__device__ __forceinline__ float2 unpack2(unsigned int p) {
    union { unsigned int u; __half2 h; } cv;
    cv.u = p;
    return __half22float2(cv.h);
}

// ---- Pass 1: pack lut fp32 -> fp16 r-pairs: ws[c*CH_STRIDE+i] = (v[i], v[i+1])
__global__ __launch_bounds__(256)
void lut_pack_kernel(const float* __restrict__ lut, unsigned int* __restrict__ W) {
    const int t = blockIdx.x * 256 + (int)threadIdx.x;
    if (t >= 3 * LUT_N) return;
    const int c = t / LUT_N;
    const int i = t - c * LUT_N;
    const float a = lut[t];
    const float b = (i + 1 < LUT_N) ? lut[t + 1] : 0.0f;
    W[c * CH_STRIDE + i] = pack2(a, b);
}

// ---- Pass 2: main interpolation, one block per chunk (1 block/CU), all 3
// channels per block, LDS re-staged per channel via async DMA.
__global__ __launch_bounds__(THREADS)
void lut3d_trilerp_kernel(const unsigned int* __restrict__ Wsrc,
                          const float* __restrict__ x,
                          float* __restrict__ out) {
    extern __shared__ __align__(16) unsigned int W[];  // CH_STRIDE u32 = 143,760 B

    const int t     = (int)threadIdx.x;
    const int chunk = blockIdx.x;                      // [0, 256)

    const float4* x4 = (const float4*)x;
    float4*       o4 = (float4*)out;
    const int g0 = chunk * (NGROUPS / NCHUNKS) + t;

    // ---- Phase A1: issue ALL x loads first (critical HBM latency+BW term).
    float4 R[ITERS], G[ITERS], B[ITERS];
    int ibase[ITERS];
#pragma unroll
    for (int it = 0; it < ITERS; ++it) {
        const int g     = g0 + it * THREADS;
        const int b_img = g >> 18;            // g / HW4  (HW4 = 2^18)
        const int hw4   = g & (HW4 - 1);
        ibase[it] = b_img * 3 * HW4 + hw4;
        R[it] = x4[ibase[it]];
        G[it] = x4[ibase[it] + HW4];
        B[it] = x4[ibase[it] + 2 * HW4];
    }

    // ---- Phase A2: DMA-stage channel 0 while x is in flight.
#pragma unroll
    for (int s = 0; s < 9; ++s) {
        const int gid = s * THREADS + t;
        if (gid < STAGE_G) {
            __builtin_amdgcn_global_load_lds(
                (const __attribute__((address_space(1))) void*)(Wsrc + gid * 4),
                (__attribute__((address_space(3))) void*)(W + gid * 4),
                16, 0, 0);
        }
    }

    // ---- Phase A3: idx + deltas, consuming x as it lands.
    int   idx[ITERS][4];
    float dr[ITERS][4], dg[ITERS][4], db[ITERS][4];
#pragma unroll
    for (int it = 0; it < ITERS; ++it) {
        const float rr[4] = {R[it].x, R[it].y, R[it].z, R[it].w};
        const float gg[4] = {G[it].x, G[it].y, G[it].z, G[it].w};
        const float bb[4] = {B[it].x, B[it].y, B[it].z, B[it].w};
#pragma unroll
        for (int k = 0; k < 4; ++k) {
            const float sr = rr[k] * 32.0f;
            const float sg = gg[k] * 32.0f;
            const float sb = bb[k] * 32.0f;
            const float fr = fminf(fmaxf(floorf(sr), 0.0f), 31.0f);
            const float fg = fminf(fmaxf(floorf(sg), 0.0f), 31.0f);
            const float fb = fminf(fmaxf(floorf(sb), 0.0f), 31.0f);
            dr[it][k] = sr - fr;
            dg[it][k] = sg - fg;
            db[it][k] = sb - fb;
            idx[it][k] = ((int)fb * LUT_D + (int)fg) * LUT_D + (int)fr;
        }
    }

    __syncthreads();   // drains x loads + DMA (vmcnt 0) before first gather

    // ---- Phase B: channels, gather/lerp/store; cheap DMA switch between.
#pragma unroll
    for (int c = 0; c < 3; ++c) {
#pragma unroll
        for (int it = 0; it < ITERS; ++it) {
            // 8 corners per pixel as 4 fp16-pairs -> 2 ds_read2_b32 per pixel.
            unsigned int qA[4], qB[4], qC[4], qD[4];
#pragma unroll
            for (int k = 0; k < 4; ++k) {
                const int i0 = idx[it][k];
                qA[k] = W[i0];                       // (c000, c001)
                qB[k] = W[i0 + LUT_D];               // (c010, c011)
                qC[k] = W[i0 + LUT_DD];              // (c100, c101)
                qD[k] = W[i0 + LUT_DD + LUT_D];      // (c110, c111)
            }
            float oo[4];
#pragma unroll
            for (int k = 0; k < 4; ++k) {
                const float2 a00 = unpack2(qA[k]);
                const float2 a01 = unpack2(qB[k]);
                const float2 a10 = unpack2(qC[k]);
                const float2 a11 = unpack2(qD[k]);
                const float l00 = a00.x + dr[it][k] * (a00.y - a00.x);
                const float l01 = a01.x + dr[it][k] * (a01.y - a01.x);
                const float l10 = a10.x + dr[it][k] * (a10.y - a10.x);
                const float l11 = a11.x + dr[it][k] * (a11.y - a11.x);
                const float l0  = l00 + dg[it][k] * (l01 - l00);
                const float l1  = l10 + dg[it][k] * (l11 - l10);
                oo[k] = l0 + db[it][k] * (l1 - l0);
            }
            vfloat4 v = {oo[0], oo[1], oo[2], oo[3]};
            __builtin_nontemporal_store(v, (vfloat4*)&o4[ibase[it] + c * HW4]);
        }

        if (c < 2) {
            __syncthreads();   // all gathers of channel c done before overwrite
            const unsigned int* src = Wsrc + (c + 1) * CH_STRIDE;
#pragma unroll
            for (int s = 0; s < 9; ++s) {
                const int gid = s * THREADS + t;
                if (gid < STAGE_G) {
                    __builtin_amdgcn_global_load_lds(
                        (const __attribute__((address_space(1))) void*)(src + gid * 4),
                        (__attribute__((address_space(3))) void*)(W + gid * 4),
                        16, 0, 0);
                }
            }
            __syncthreads();   // DMA drained (vmcnt 0) -> channel c+1 visible
        }
    }
}

extern "C" void kernel_launch(void* const* d_in, const int* in_sizes, int n_in,
                              void* d_out, int out_size, void* d_ws, size_t ws_size,
                              hipStream_t stream) {
    const float*  lut = (const float*)d_in[0];   // [3, 33, 33, 33]
    const float*  x   = (const float*)d_in[1];   // [4, 3, 1024, 1024]
    float*        out = (float*)d_out;
    unsigned int* W   = (unsigned int*)d_ws;     // 3*CH_STRIDE u32 = 431,280 B

    const int pack_grid = (3 * LUT_N + 255) / 256;   // 422
    lut_pack_kernel<<<pack_grid, 256, 0, stream>>>(lut, W);

    const size_t lds_bytes = (size_t)CH_STRIDE * 4;  // 143,760 B -> 1 block/CU
    lut3d_trilerp_kernel<<<NCHUNKS, THREADS, lds_bytes, stream>>>(W, x, out);
}